// Round 1
// 120.765 us; speedup vs baseline: 1.0372x; 1.0372x over previous
//
#include <hip/hip_runtime.h>

#define TW 32
#define TH 48
#define HR 58          // TH + 10 intermediate rows
#define IMG_W 512
#define OUT_W 502      // 512 - 11 + 1
#define CH_STRIDE (3 * IMG_W * IMG_W)
#define GX 16
#define GY 11          // ceil(502/48)
#define GZ 16
#define NBLK (GX * GY * GZ)   // 2816

// Phase 1: 232 threads (91% of block), each computes 8 consecutive horizontal-conv
//          outputs for one of 58 rows, loading a 20-float span straight from global
//          (float4-aligned), writing 5 intermediate fields to LDS as float4.
// Phase 2: 256 threads, each owns (column, 6-row strip): reads 16 rows x 5
//          fields once each (register accumulation), applies SSIM, reduces.
// Gaussian weights hardcoded (double-precision derived, <=1 ulp vs float expf
// path) — removes 11 expf + normalize per thread and frees ~11 VGPRs.
__global__ __launch_bounds__(256) void ssim_main_kernel(
    const float* __restrict__ sr_img,
    const float* __restrict__ hr_img,
    float* __restrict__ partial)
{
    __shared__ float hf[5][HR][TW];   // m1, m2, x2, y2, xy  (37120 B)
    __shared__ float red[4];

    const int t  = threadIdx.x;
    const int x0 = blockIdx.x * TW;
    const int y0 = blockIdx.y * TH;
    const int b  = blockIdx.z;

    // 1D separable Gaussian, sigma=1.5, size=11, normalized (compile-time consts)
    const float W[11] = {
        0.00102838f, 0.00759876f, 0.03600077f, 0.10936069f, 0.21300554f,
        0.26601173f,
        0.21300554f, 0.10936069f, 0.03600077f, 0.00759876f, 0.00102838f
    };

    const float* __restrict__ hrp = hr_img + (size_t)b * CH_STRIDE;  // channel 0
    const float* __restrict__ srp = sr_img + (size_t)b * CH_STRIDE;

    // ---------- Phase 1: horizontal 11-tap, direct from global ----------
    if (t < 4 * HR) {             // 232 threads
        int r  = t >> 2;          // 0..57
        int c0 = (t & 3) * 8;     // 0,8,16,24
        int gy = y0 + r; if (gy > IMG_W - 1) gy = IMG_W - 1;
        const float4* hrow = (const float4*)(hrp + (size_t)gy * IMG_W + x0 + c0);
        const float4* srow = (const float4*)(srp + (size_t)gy * IMG_W + x0 + c0);

        float h[20], s[20];
#pragma unroll
        for (int q = 0; q < 5; ++q) {
            float4 va = hrow[q];
            h[4*q] = va.x; h[4*q+1] = va.y; h[4*q+2] = va.z; h[4*q+3] = va.w;
            float4 vb = srow[q];
            s[4*q] = vb.x; s[4*q+1] = vb.y; s[4*q+2] = vb.z; s[4*q+3] = vb.w;
        }

        float m1[8], m2[8], x2[8], y2[8], xy[8];
#pragma unroll
        for (int j = 0; j < 8; ++j) { m1[j]=0.f; m2[j]=0.f; x2[j]=0.f; y2[j]=0.f; xy[j]=0.f; }
#pragma unroll
        for (int k = 0; k < 11; ++k) {
            float wk = W[k];
#pragma unroll
            for (int j = 0; j < 8; ++j) {
                float a = h[j + k], bb = s[j + k];
                float u = wk * a, v = wk * bb;
                m1[j] += u;      m2[j] += v;
                x2[j] += u * a;  y2[j] += v * bb;  xy[j] += u * bb;
            }
        }
        *(float4*)&hf[0][r][c0]   = make_float4(m1[0],m1[1],m1[2],m1[3]);
        *(float4*)&hf[0][r][c0+4] = make_float4(m1[4],m1[5],m1[6],m1[7]);
        *(float4*)&hf[1][r][c0]   = make_float4(m2[0],m2[1],m2[2],m2[3]);
        *(float4*)&hf[1][r][c0+4] = make_float4(m2[4],m2[5],m2[6],m2[7]);
        *(float4*)&hf[2][r][c0]   = make_float4(x2[0],x2[1],x2[2],x2[3]);
        *(float4*)&hf[2][r][c0+4] = make_float4(x2[4],x2[5],x2[6],x2[7]);
        *(float4*)&hf[3][r][c0]   = make_float4(y2[0],y2[1],y2[2],y2[3]);
        *(float4*)&hf[3][r][c0+4] = make_float4(y2[4],y2[5],y2[6],y2[7]);
        *(float4*)&hf[4][r][c0]   = make_float4(xy[0],xy[1],xy[2],xy[3]);
        *(float4*)&hf[4][r][c0+4] = make_float4(xy[4],xy[5],xy[6],xy[7]);
    }
    __syncthreads();

    // ---------- Phase 2: vertical 11-tap, 6-row strips, all 256 threads ----------
    const float C1v = 1e-4f, C2v = 9e-4f;
    float local = 0.f;
    {
        int c  = t & 31;
        int r0 = (t >> 5) * 6;    // 0,6,...,42

        float am1[6], am2[6], ax2[6], ay2[6], axy[6];
#pragma unroll
        for (int j = 0; j < 6; ++j) { am1[j]=0.f; am2[j]=0.f; ax2[j]=0.f; ay2[j]=0.f; axy[j]=0.f; }

#pragma unroll
        for (int i = 0; i < 16; ++i) {
            float vm1 = hf[0][r0 + i][c];
            float vm2 = hf[1][r0 + i][c];
            float vx2 = hf[2][r0 + i][c];
            float vy2 = hf[3][r0 + i][c];
            float vxy = hf[4][r0 + i][c];
#pragma unroll
            for (int j = 0; j < 6; ++j) {
                int k = i - j;                 // compile-time: no predication emitted
                if (k >= 0 && k <= 10) {
                    float wk = W[k];
                    am1[j] += wk * vm1;  am2[j] += wk * vm2;
                    ax2[j] += wk * vx2;  ay2[j] += wk * vy2;
                    axy[j] += wk * vxy;
                }
            }
        }

        int ox = x0 + c;
#pragma unroll
        for (int j = 0; j < 6; ++j) {
            int oy = y0 + r0 + j;
            if (oy < OUT_W && ox < OUT_W) {
                float m1 = am1[j], m2 = am2[j];
                float mu1s = m1 * m1, mu2s = m2 * m2, m12 = m1 * m2;
                float s1 = ax2[j] - mu1s, s2 = ay2[j] - mu2s, s12 = axy[j] - m12;
                float num = (2.f * m12 + C1v) * (2.f * s12 + C2v);
                float den = (mu1s + mu2s + C1v) * (s1 + s2 + C2v);
                local += num / den;
            }
        }
    }

    // ---------- Reduction: wave shuffle + tiny LDS ----------
#pragma unroll
    for (int off = 32; off > 0; off >>= 1)
        local += __shfl_down(local, off);
    if ((t & 63) == 0) red[t >> 6] = local;
    __syncthreads();
    if (t == 0) {
        int blk = (blockIdx.z * GY + blockIdx.y) * GX + blockIdx.x;
        partial[blk] = red[0] + red[1] + red[2] + red[3];
    }
}

__global__ __launch_bounds__(256) void ssim_finalize(
    const float* __restrict__ partial, float* __restrict__ out)
{
    __shared__ float red[4];
    int t = threadIdx.x;
    float s = 0.f;
#pragma unroll
    for (int i = 0; i < NBLK / 256; ++i)       // 11 iterations
        s += partial[t + i * 256];
#pragma unroll
    for (int off = 32; off > 0; off >>= 1)
        s += __shfl_down(s, off);
    if ((t & 63) == 0) red[t >> 6] = s;
    __syncthreads();
    if (t == 0)
        out[0] = (red[0] + red[1] + red[2] + red[3]) * (1.0f / (16.0f * 502.0f * 502.0f));
}

extern "C" void kernel_launch(void* const* d_in, const int* in_sizes, int n_in,
                              void* d_out, int out_size, void* d_ws, size_t ws_size,
                              hipStream_t stream)
{
    const float* sr = (const float*)d_in[0];  // sr_image
    const float* hr = (const float*)d_in[1];  // hr_image
    float* out = (float*)d_out;
    float* partial = (float*)d_ws;            // 2816 floats, fully overwritten

    dim3 grid(GX, GY, GZ);
    ssim_main_kernel<<<grid, 256, 0, stream>>>(sr, hr, partial);
    ssim_finalize<<<1, 256, 0, stream>>>(partial, out);
}

// Round 2
// 118.846 us; speedup vs baseline: 1.0540x; 1.0161x over previous
//
#include <hip/hip_runtime.h>

#define TW 32
#define TH 48
#define HR 58          // TH + 10 intermediate rows
#define IMG_W 512
#define OUT_W 502      // 512 - 11 + 1
#define CH_STRIDE (3 * IMG_W * IMG_W)
#define GX 16
#define GY 11          // ceil(502/48)
#define GZ 16
#define NBLK (GX * GY * GZ)   // 2816

typedef float f2 __attribute__((ext_vector_type(2)));

// Packed-pair SSIM kernel.
// Fields packed as float2: M12=(mu1,mu2) driven by (h,s); SQ=(x2,y2) driven by
// (h,s)^2; XY scalar. float2 arithmetic lowers to v_pk_fma_f32/v_pk_mul_f32
// (gfx90a+ packed fp32) -> ~2x issue-rate on 4 of 5 conv chains.
// LDS row strides padded (+2 elems, 272B/144B, 16B-aligned) so phase-1 b128
// stores and phase-2 b64/b32 reads all sit at the 2-way bank floor (was 4-way
// on stores).
__global__ __launch_bounds__(256, 4) void ssim_main_kernel(
    const float* __restrict__ sr_img,
    const float* __restrict__ hr_img,
    float* __restrict__ partial)
{
    __shared__ __align__(16) f2    M12[HR][TW + 2];   // 15776 B
    __shared__ __align__(16) f2    SQ [HR][TW + 2];   // 15776 B
    __shared__ __align__(16) float XY [HR][TW + 4];   // 8352 B
    __shared__ float red[4];                          // total 39920 B -> 4 blk/CU

    const int t  = threadIdx.x;
    const int x0 = blockIdx.x * TW;
    const int y0 = blockIdx.y * TH;
    const int b  = blockIdx.z;

    // 1D separable Gaussian, sigma=1.5, size=11, normalized
    const float Wf[11] = {
        0.00102838f, 0.00759876f, 0.03600077f, 0.10936069f, 0.21300554f,
        0.26601173f,
        0.21300554f, 0.10936069f, 0.03600077f, 0.00759876f, 0.00102838f
    };
    const f2 W2[11] = {
        {0.00102838f,0.00102838f}, {0.00759876f,0.00759876f},
        {0.03600077f,0.03600077f}, {0.10936069f,0.10936069f},
        {0.21300554f,0.21300554f}, {0.26601173f,0.26601173f},
        {0.21300554f,0.21300554f}, {0.10936069f,0.10936069f},
        {0.03600077f,0.03600077f}, {0.00759876f,0.00759876f},
        {0.00102838f,0.00102838f}
    };

    const float* __restrict__ hrp = hr_img + (size_t)b * CH_STRIDE;  // channel 0
    const float* __restrict__ srp = sr_img + (size_t)b * CH_STRIDE;

    // ---------- Phase 1: horizontal 11-tap, direct from global ----------
    if (t < 4 * HR) {             // 232 threads
        int r  = t >> 2;          // 0..57
        int c0 = (t & 3) * 8;     // 0,8,16,24  (output columns / float2 slots)
        int gy = y0 + r; if (gy > IMG_W - 1) gy = IMG_W - 1;
        const float4* hrow = (const float4*)(hrp + (size_t)gy * IMG_W + x0 + c0);
        const float4* srow = (const float4*)(srp + (size_t)gy * IMG_W + x0 + c0);

        f2 hs[20];
#pragma unroll
        for (int q = 0; q < 5; ++q) {
            float4 va = hrow[q];
            float4 vb = srow[q];
            hs[4*q+0] = (f2){va.x, vb.x};
            hs[4*q+1] = (f2){va.y, vb.y};
            hs[4*q+2] = (f2){va.z, vb.z};
            hs[4*q+3] = (f2){va.w, vb.w};
        }

        f2 a12[8], asq[8];
        float axy[8];
#pragma unroll
        for (int j = 0; j < 8; ++j) {
            a12[j] = (f2){0.f, 0.f};
            asq[j] = (f2){0.f, 0.f};
            axy[j] = 0.f;
        }
#pragma unroll
        for (int k = 0; k < 11; ++k) {
            f2 wp = W2[k];
            float wk = Wf[k];
#pragma unroll
            for (int j = 0; j < 8; ++j) {
                f2 x = hs[j + k];
                a12[j] += wp * x;            // v_pk_fma: mu1, mu2
                asq[j] += wp * (x * x);      // v_pk_mul + v_pk_fma: x2, y2
                axy[j]  = fmaf(wk, x.x * x.y, axy[j]);   // scalar: xy
            }
        }
        // stores: float4 = 2 float2 slots; row strides 16B-aligned
        *(float4*)&M12[r][c0+0] = make_float4(a12[0].x,a12[0].y,a12[1].x,a12[1].y);
        *(float4*)&M12[r][c0+2] = make_float4(a12[2].x,a12[2].y,a12[3].x,a12[3].y);
        *(float4*)&M12[r][c0+4] = make_float4(a12[4].x,a12[4].y,a12[5].x,a12[5].y);
        *(float4*)&M12[r][c0+6] = make_float4(a12[6].x,a12[6].y,a12[7].x,a12[7].y);
        *(float4*)&SQ [r][c0+0] = make_float4(asq[0].x,asq[0].y,asq[1].x,asq[1].y);
        *(float4*)&SQ [r][c0+2] = make_float4(asq[2].x,asq[2].y,asq[3].x,asq[3].y);
        *(float4*)&SQ [r][c0+4] = make_float4(asq[4].x,asq[4].y,asq[5].x,asq[5].y);
        *(float4*)&SQ [r][c0+6] = make_float4(asq[6].x,asq[6].y,asq[7].x,asq[7].y);
        *(float4*)&XY [r][c0+0] = make_float4(axy[0],axy[1],axy[2],axy[3]);
        *(float4*)&XY [r][c0+4] = make_float4(axy[4],axy[5],axy[6],axy[7]);
    }
    __syncthreads();

    // ---------- Phase 2: vertical 11-tap, 6-row strips, all 256 threads ----------
    const float C1v = 1e-4f, C2v = 9e-4f;
    float local = 0.f;
    {
        int c  = t & 31;
        int r0 = (t >> 5) * 6;    // 0,6,...,42

        f2 am[6], as_[6];
        float ax[6];
#pragma unroll
        for (int j = 0; j < 6; ++j) {
            am[j] = (f2){0.f, 0.f};
            as_[j] = (f2){0.f, 0.f};
            ax[j] = 0.f;
        }

#pragma unroll
        for (int i = 0; i < 16; ++i) {
            f2 vm = M12[r0 + i][c];      // ds_read_b64
            f2 vs = SQ [r0 + i][c];      // ds_read_b64
            float vx = XY[r0 + i][c];    // ds_read_b32
#pragma unroll
            for (int j = 0; j < 6; ++j) {
                int k = i - j;           // compile-time per (i,j)
                if (k >= 0 && k <= 10) {
                    am[j]  += W2[k] * vm;
                    as_[j] += W2[k] * vs;
                    ax[j]   = fmaf(Wf[k], vx, ax[j]);
                }
            }
        }

        int ox = x0 + c;
#pragma unroll
        for (int j = 0; j < 6; ++j) {
            int oy = y0 + r0 + j;
            if (oy < OUT_W && ox < OUT_W) {
                float m1 = am[j].x, m2 = am[j].y;
                float mu1s = m1 * m1, mu2s = m2 * m2, m12 = m1 * m2;
                float s1 = as_[j].x - mu1s, s2 = as_[j].y - mu2s, s12 = ax[j] - m12;
                float num = (2.f * m12 + C1v) * (2.f * s12 + C2v);
                float den = (mu1s + mu2s + C1v) * (s1 + s2 + C2v);
                local += num / den;
            }
        }
    }

    // ---------- Reduction: wave shuffle + tiny LDS ----------
#pragma unroll
    for (int off = 32; off > 0; off >>= 1)
        local += __shfl_down(local, off);
    if ((t & 63) == 0) red[t >> 6] = local;
    __syncthreads();
    if (t == 0) {
        int blk = (blockIdx.z * GY + blockIdx.y) * GX + blockIdx.x;
        partial[blk] = red[0] + red[1] + red[2] + red[3];
    }
}

__global__ __launch_bounds__(256) void ssim_finalize(
    const float* __restrict__ partial, float* __restrict__ out)
{
    __shared__ float red[4];
    int t = threadIdx.x;
    float s = 0.f;
#pragma unroll
    for (int i = 0; i < NBLK / 256; ++i)       // 11 iterations
        s += partial[t + i * 256];
#pragma unroll
    for (int off = 32; off > 0; off >>= 1)
        s += __shfl_down(s, off);
    if ((t & 63) == 0) red[t >> 6] = s;
    __syncthreads();
    if (t == 0)
        out[0] = (red[0] + red[1] + red[2] + red[3]) * (1.0f / (16.0f * 502.0f * 502.0f));
}

extern "C" void kernel_launch(void* const* d_in, const int* in_sizes, int n_in,
                              void* d_out, int out_size, void* d_ws, size_t ws_size,
                              hipStream_t stream)
{
    const float* sr = (const float*)d_in[0];  // sr_image
    const float* hr = (const float*)d_in[1];  // hr_image
    float* out = (float*)d_out;
    float* partial = (float*)d_ws;            // 2816 floats, fully overwritten

    dim3 grid(GX, GY, GZ);
    ssim_main_kernel<<<grid, 256, 0, stream>>>(sr, hr, partial);
    ssim_finalize<<<1, 256, 0, stream>>>(partial, out);
}